// Round 1
// baseline (231.962 us; speedup 1.0000x reference)
//
#include <hip/hip_runtime.h>
#include <stdint.h>

// ConformerSelfAttention (B=8,T=1024,D=512,H=8,DK=64) for gfx950.
// Pipeline: prep(weightsT->bf16, pos_emb->bf16, xlens tail) -> LN -> QKV GEMM
// -> P GEMM -> flash rel-pos attention -> out GEMM (+bias) -> d_out fp32.

typedef __attribute__((ext_vector_type(8))) short s8v;
typedef __attribute__((ext_vector_type(4))) short s4v;
typedef __attribute__((ext_vector_type(4))) float f4v;
typedef unsigned short u16;

#define MFMA(a, b, c) __builtin_amdgcn_mfma_f32_16x16x32_bf16((a), (b), (c), 0, 0, 0)

__device__ __forceinline__ float bf2f(u16 u) {
    union { unsigned i; float f; } w; w.i = ((unsigned)u) << 16; return w.f;
}
__device__ __forceinline__ u16 f2bf(float f) {
    union { float f; unsigned i; } w; w.f = f;
    return (u16)((w.i + 0x7FFFu + ((w.i >> 16) & 1u)) >> 16);
}

// ---------------- prep: W^T->bf16 (5 mats), pos_emb->bf16, xlens tail ----------------
__global__ __launch_bounds__(256) void prep_k(
    const float* __restrict__ Wq, const float* __restrict__ Wk, const float* __restrict__ Wv,
    const float* __restrict__ Wpos, const float* __restrict__ Wo,
    const float* __restrict__ pos_emb, const int* __restrict__ xlens,
    u16* __restrict__ wt, u16* __restrict__ pe, float* __restrict__ tail)
{
    int bid = blockIdx.x, tid = threadIdx.x;
    if (bid < 1280) {
        // transpose-convert one 32x32 tile: wt[mat][n][k] = bf16(W[k][n])
        __shared__ float lt[32][33];
        int mat = bid >> 8, tile = bid & 255;
        int kt = (tile >> 4) << 5, nt = (tile & 15) << 5;
        const float* W = mat == 0 ? Wq : mat == 1 ? Wk : mat == 2 ? Wv : mat == 3 ? Wpos : Wo;
        int ty = tid >> 3, tx = tid & 7;
        float4 vv = *(const float4*)&W[(kt + ty) * 512 + nt + tx * 4];
        lt[ty][tx * 4 + 0] = vv.x; lt[ty][tx * 4 + 1] = vv.y;
        lt[ty][tx * 4 + 2] = vv.z; lt[ty][tx * 4 + 3] = vv.w;
        __syncthreads();
        int nl = tid >> 3, k4 = (tid & 7) * 4;
        union { s4v v; u16 u[4]; } ob;
        #pragma unroll
        for (int e = 0; e < 4; ++e) ob.u[e] = f2bf(lt[k4 + e][nl]);
        *(s4v*)&wt[mat * 262144 + (nt + nl) * 512 + kt + k4] = ob.v;
    } else if (bid < 2304) {
        int i = (bid - 1280) * 1024 + tid * 4;
        union { s4v v; u16 u[4]; } ob;
        if (i < 2047 * 512) {
            float4 vv = *(const float4*)&pos_emb[i];
            ob.u[0] = f2bf(vv.x); ob.u[1] = f2bf(vv.y);
            ob.u[2] = f2bf(vv.z); ob.u[3] = f2bf(vv.w);
        } else {
            ob.u[0] = ob.u[1] = ob.u[2] = ob.u[3] = 0;  // pad row 2047 with zeros
        }
        *(s4v*)&pe[i] = ob.v;
    } else {
        if (tid < 8) tail[tid] = (float)xlens[tid];
    }
}

// ---------------- LayerNorm: one wave per token, bf16 out ----------------
__global__ __launch_bounds__(256) void ln_k(
    const float* __restrict__ x, const float* __restrict__ gamma,
    const float* __restrict__ beta, u16* __restrict__ xn)
{
    int tok = blockIdx.x * 4 + (threadIdx.x >> 6);
    int l = threadIdx.x & 63;
    const float* xr = x + (size_t)tok * 512 + l * 8;
    float v[8];
    {
        float4 a = *(const float4*)xr; float4 b = *(const float4*)(xr + 4);
        v[0] = a.x; v[1] = a.y; v[2] = a.z; v[3] = a.w;
        v[4] = b.x; v[5] = b.y; v[6] = b.z; v[7] = b.w;
    }
    float s = 0.f, q = 0.f;
    #pragma unroll
    for (int e = 0; e < 8; ++e) { s += v[e]; q += v[e] * v[e]; }
    #pragma unroll
    for (int off = 1; off < 64; off <<= 1) { s += __shfl_xor(s, off); q += __shfl_xor(q, off); }
    float mean = s * (1.f / 512.f);
    float var = q * (1.f / 512.f) - mean * mean;
    float inv = rsqrtf(var + 1e-5f);
    union { s8v v; u16 u[8]; } ob;
    #pragma unroll
    for (int e = 0; e < 8; ++e)
        ob.u[e] = f2bf((v[e] - mean) * inv * gamma[l * 8 + e] + beta[l * 8 + e]);
    *(s8v*)&xn[(size_t)tok * 512 + l * 8] = ob.v;
}

// ---------------- GEMM: C[M x N] = A[M x 512] @ W^T rows, bf16 MFMA ----------------
// mode 0: fused QKV (N=1536, per-head layout out, +bias)
// mode 1: P = pos_emb @ WposT (M=2047 guard, (H,2047,DK) layout)
// mode 2: out = AO @ WoT + bo  (fp32 to d_out)
__global__ __launch_bounds__(256) void gemm_k(
    const u16* __restrict__ A,
    const u16* __restrict__ W0, const u16* __restrict__ W1, const u16* __restrict__ W2,
    const float* __restrict__ b0, const float* __restrict__ b1, const float* __restrict__ b2,
    int mode, u16* __restrict__ o0, u16* __restrict__ o1, u16* __restrict__ o2,
    float* __restrict__ of)
{
    __shared__ u16 Al[128 * 40];   // stride 40 elems (80B): 16B-aligned, 2-way banks max
    __shared__ u16 Bl[128 * 40];
    int tid = threadIdx.x, l = tid & 63, wid = tid >> 6;
    int wr = wid >> 1, wc = wid & 1;
    int m0 = blockIdx.x << 7, n0 = blockIdx.y << 7;
    int mat = n0 >> 9, nb = n0 & 511;
    const u16* W = mat == 0 ? W0 : mat == 1 ? W1 : W2;
    const float* bias = mat == 0 ? b0 : mat == 1 ? b1 : b2;
    int r = l & 15, kq = (l >> 4) << 3;
    int srow = tid >> 2, sc = (tid & 3) << 3;
    f4v zero = {0.f, 0.f, 0.f, 0.f};
    f4v acc[4][4];
    #pragma unroll
    for (int i = 0; i < 4; ++i)
        #pragma unroll
        for (int j = 0; j < 4; ++j) acc[i][j] = zero;

    for (int k0 = 0; k0 < 512; k0 += 32) {
        __syncthreads();
        #pragma unroll
        for (int it = 0; it < 2; ++it) {
            int row = it * 64 + srow;
            *(s8v*)&Al[row * 40 + sc] = *(const s8v*)&A[(m0 + row) * 512 + k0 + sc];
            *(s8v*)&Bl[row * 40 + sc] = *(const s8v*)&W[(nb + row) * 512 + k0 + sc];
        }
        __syncthreads();
        s8v af[4], bfv[4];
        #pragma unroll
        for (int i = 0; i < 4; ++i) af[i] = *(const s8v*)&Al[(wr * 64 + i * 16 + r) * 40 + kq];
        #pragma unroll
        for (int i = 0; i < 4; ++i) bfv[i] = *(const s8v*)&Bl[(wc * 64 + i * 16 + r) * 40 + kq];
        #pragma unroll
        for (int i = 0; i < 4; ++i)
            #pragma unroll
            for (int j = 0; j < 4; ++j) acc[i][j] = MFMA(af[i], bfv[j], acc[i][j]);
    }

    #pragma unroll
    for (int i = 0; i < 4; ++i)
        #pragma unroll
        for (int j = 0; j < 4; ++j) {
            int ncol = nb + wc * 64 + j * 16 + r;
            #pragma unroll
            for (int jj = 0; jj < 4; ++jj) {
                int m = m0 + wr * 64 + i * 16 + ((l >> 4) << 2) + jj;
                float val = acc[i][j][jj];
                if (mode == 0) {
                    val += bias[ncol];
                    u16* dst = mat == 0 ? o0 : mat == 1 ? o1 : o2;
                    int bb = m >> 10, t = m & 1023, hh = ncol >> 6, dk = ncol & 63;
                    dst[((bb * 8 + hh) * 1024 + t) * 64 + dk] = f2bf(val);
                } else if (mode == 1) {
                    if (m < 2047) {
                        int hh = ncol >> 6, dk = ncol & 63;
                        o0[(hh * 2047 + m) * 64 + dk] = f2bf(val);
                    }
                } else {
                    of[(size_t)m * 512 + ncol] = val + b0[ncol];
                }
            }
        }
}

// ---------------- flash rel-pos attention ----------------
// grid (16 t-tiles, 64 b*h). block = 4 waves, each wave owns 16 t-rows.
// scores[t,s] = ((q+u)[t].k[s] + (q+v)[t].p[T-1+s-t]) / 8 ; online softmax; O = P@V.
__global__ __launch_bounds__(256) void attn_k(
    const u16* __restrict__ q, const u16* __restrict__ k, const u16* __restrict__ v,
    const u16* __restrict__ p, const float* __restrict__ pbu, const float* __restrict__ pbv,
    const int* __restrict__ xlens, u16* __restrict__ ao)
{
    __shared__ u16 Qs[64 * 72];
    __shared__ u16 Ks[64 * 72];
    __shared__ u16 Ps[128 * 72];
    __shared__ u16 Vt[64 * 64];       // V transposed [dk][s], XOR-swizzled k-blocks
    __shared__ u16 Tb[4][16 * 136];   // per-wave scratch: bd band (bf16) then P A-tile

    int tid = threadIdx.x, l = tid & 63, wid = tid >> 6;
    int r = l & 15, kq = (l >> 4) << 3;
    int t0 = blockIdx.x << 6;
    int bh = blockIdx.y, b = bh >> 3, h = bh & 7;
    int xlen = xlens[b];
    const u16* qh = q + (size_t)bh * 1024 * 64;
    const u16* kh = k + (size_t)bh * 1024 * 64;
    const u16* vh = v + (size_t)bh * 1024 * 64;
    const u16* ph = p + (size_t)h * 2047 * 64;

    // stage Q tile
    #pragma unroll
    for (int it = 0; it < 2; ++it) {
        int e = it * 2048 + tid * 8, row = e >> 6, c = e & 63;
        *(s8v*)&Qs[row * 72 + c] = *(const s8v*)&qh[(t0 + row) * 64 + c];
    }
    __syncthreads();
    // build (q+u) and (q+v) A-fragments for this wave's 16 rows
    s8v qu[2], qv2[2];
    #pragma unroll
    for (int ks = 0; ks < 2; ++ks) {
        union { s8v v; u16 u[8]; } src, du, dv;
        src.v = *(const s8v*)&Qs[(wid * 16 + r) * 72 + ks * 32 + kq];
        #pragma unroll
        for (int e = 0; e < 8; ++e) {
            float qf = bf2f(src.u[e]);
            int kk = ks * 32 + kq + e;
            du.u[e] = f2bf(qf + pbu[h * 64 + kk]);
            dv.u[e] = f2bf(qf + pbv[h * 64 + kk]);
        }
        qu[ks] = du.v; qv2[ks] = dv.v;
    }

    float mst[4] = {-1e30f, -1e30f, -1e30f, -1e30f};
    float lst[4] = {0.f, 0.f, 0.f, 0.f};
    f4v zero = {0.f, 0.f, 0.f, 0.f};
    f4v o[4];
    #pragma unroll
    for (int i = 0; i < 4; ++i) o[i] = zero;

    u16* tb = &Tb[wid][0];
    int nst = (xlen + 63) >> 6;   // skip fully-masked key tiles
    for (int s0i = 0; s0i < nst; ++s0i) {
        int s0 = s0i << 6;
        __syncthreads();
        // stage K
        #pragma unroll
        for (int it = 0; it < 2; ++it) {
            int e = it * 2048 + tid * 8, row = e >> 6, c = e & 63;
            *(s8v*)&Ks[row * 72 + c] = *(const s8v*)&kh[(s0 + row) * 64 + c];
        }
        // stage V transposed with XOR swizzle (write u16 scatter; reads are b128)
        #pragma unroll
        for (int it = 0; it < 2; ++it) {
            int e = it * 2048 + tid * 8, row = e >> 6, c = e & 63;
            union { s8v v; u16 u[8]; } vv;
            vv.v = *(const s8v*)&vh[(s0 + row) * 64 + c];
            #pragma unroll
            for (int e2 = 0; e2 < 8; ++e2) {
                int dk = c + e2;
                int swz = (dk ^ (dk >> 3)) & 7;
                Vt[dk * 64 + ((((row >> 3) ^ swz)) << 3) + (row & 7)] = vv.u[e2];
            }
        }
        // stage P band: rows nbase..nbase+127 (clamped; clamped rows are never gathered)
        int nbase = 960 + s0 - t0;
        #pragma unroll
        for (int it = 0; it < 4; ++it) {
            int e = it * 2048 + tid * 8, row = e >> 6, c = e & 63;
            int g = nbase + row; g = g > 2046 ? 2046 : g;
            *(s8v*)&Ps[row * 72 + c] = *(const s8v*)&ph[g * 64 + c];
        }
        __syncthreads();

        // content scores (q+u)@K^T : 16x64 per wave
        f4v st4[4];
        #pragma unroll
        for (int nf = 0; nf < 4; ++nf) {
            f4v a = zero;
            #pragma unroll
            for (int ks = 0; ks < 2; ++ks)
                a = MFMA(qu[ks], *(const s8v*)&Ks[(nf * 16 + r) * 72 + ks * 32 + kq], a);
            st4[nf] = a;
        }
        // positional band (q+v)@P^T : 16x128 per wave -> Tb (bf16)
        #pragma unroll
        for (int pf = 0; pf < 8; ++pf) {
            f4v a = zero;
            #pragma unroll
            for (int ks = 0; ks < 2; ++ks)
                a = MFMA(qv2[ks], *(const s8v*)&Ps[(pf * 16 + r) * 72 + ks * 32 + kq], a);
            #pragma unroll
            for (int j = 0; j < 4; ++j)
                tb[(((l >> 4) << 2) + j) * 136 + pf * 16 + r] = f2bf(a[j]);
        }
        asm volatile("s_waitcnt lgkmcnt(0)" ::: "memory");
        // rel-shift gather + mask + scale
        float sv[4][4];
        #pragma unroll
        for (int j = 0; j < 4; ++j) {
            int r16 = ((l >> 4) << 2) + j;
            int ti = wid * 16 + r16;
            #pragma unroll
            for (int nf = 0; nf < 4; ++nf) {
                int si = nf * 16 + r;
                float val = (st4[nf][j] + bf2f(tb[r16 * 136 + si + 63 - ti])) * 0.125f;
                sv[nf][j] = (s0 + si >= xlen) ? -1e9f : val;
            }
        }
        asm volatile("" ::: "memory");  // keep gather loads before tb re-use stores
        // online softmax per row
        float pr[4][4];
        #pragma unroll
        for (int j = 0; j < 4; ++j) {
            float mx = fmaxf(fmaxf(sv[0][j], sv[1][j]), fmaxf(sv[2][j], sv[3][j]));
            mx = fmaxf(mx, __shfl_xor(mx, 1));
            mx = fmaxf(mx, __shfl_xor(mx, 2));
            mx = fmaxf(mx, __shfl_xor(mx, 4));
            mx = fmaxf(mx, __shfl_xor(mx, 8));
            float mnew = fmaxf(mst[j], mx);
            float alpha = __expf(mst[j] - mnew);
            float rs = 0.f;
            #pragma unroll
            for (int nf = 0; nf < 4; ++nf) {
                float e_ = __expf(sv[nf][j] - mnew); pr[nf][j] = e_; rs += e_;
            }
            rs += __shfl_xor(rs, 1); rs += __shfl_xor(rs, 2);
            rs += __shfl_xor(rs, 4); rs += __shfl_xor(rs, 8);
            lst[j] = lst[j] * alpha + rs;
            mst[j] = mnew;
            #pragma unroll
            for (int i = 0; i < 4; ++i) o[i][j] *= alpha;
        }
        // P -> LDS in A-operand layout (stride 72), then read A frags
        #pragma unroll
        for (int nf = 0; nf < 4; ++nf)
            #pragma unroll
            for (int j = 0; j < 4; ++j)
                tb[(((l >> 4) << 2) + j) * 72 + nf * 16 + r] = f2bf(pr[nf][j]);
        asm volatile("s_waitcnt lgkmcnt(0)" ::: "memory");
        s8v pa[2];
        #pragma unroll
        for (int ks = 0; ks < 2; ++ks)
            pa[ks] = *(const s8v*)&tb[r * 72 + ks * 32 + kq];
        // O += P @ V  (B frags via swizzled transposed V, single b128 each)
        #pragma unroll
        for (int i = 0; i < 4; ++i) {
            int dk = i * 16 + r;
            int swz = (dk ^ (dk >> 3)) & 7;
            #pragma unroll
            for (int ks = 0; ks < 2; ++ks) {
                int sb = ks * 32 + kq;
                s8v vb = *(const s8v*)&Vt[dk * 64 + (((sb >> 3) ^ swz) << 3)];
                o[i] = MFMA(pa[ks], vb, o[i]);
            }
        }
    }
    // normalize + write (B,T,D) bf16
    #pragma unroll
    for (int i = 0; i < 4; ++i)
        #pragma unroll
        for (int j = 0; j < 4; ++j) {
            int t = t0 + wid * 16 + ((l >> 4) << 2) + j;
            float val = o[i][j] / lst[j];
            ao[((size_t)(b * 1024 + t)) * 512 + h * 64 + i * 16 + r] = f2bf(val);
        }
}

// ---------------- launch ----------------
extern "C" void kernel_launch(void* const* d_in, const int* in_sizes, int n_in,
                              void* d_out, int out_size, void* d_ws, size_t ws_size,
                              hipStream_t stream)
{
    (void)in_sizes; (void)n_in; (void)out_size; (void)ws_size;
    const float* x     = (const float*)d_in[0];
    const int*   xlens = (const int*)d_in[1];
    const float* pos_e = (const float*)d_in[2];
    const float* gam   = (const float*)d_in[3];
    const float* bet   = (const float*)d_in[4];
    const float* Wq    = (const float*)d_in[5];
    const float* bq    = (const float*)d_in[6];
    const float* Wk    = (const float*)d_in[7];
    const float* bk    = (const float*)d_in[8];
    const float* Wv    = (const float*)d_in[9];
    const float* bv    = (const float*)d_in[10];
    const float* Wpos  = (const float*)d_in[11];
    const float* pbu   = (const float*)d_in[12];
    const float* pbv   = (const float*)d_in[13];
    const float* Wo    = (const float*)d_in[14];
    const float* bo    = (const float*)d_in[15];
    float* out = (float*)d_out;

    char* ws = (char*)d_ws;
    u16* xn = (u16*)(ws);                    // 8 MiB (8192x512 bf16); later reused as AO
    u16* qb = (u16*)(ws + 8388608);          // 8 MiB (B,H,T,DK)
    u16* kb = (u16*)(ws + 16777216);         // 8 MiB
    u16* vb = (u16*)(ws + 25165824);         // 8 MiB
    u16* pb = (u16*)(ws + 33554432);         // (H,2047,DK) bf16
    u16* pe = (u16*)(ws + 35651584);         // pos_emb bf16, padded to 2048 rows
    u16* wt = (u16*)(ws + 37748736);         // 5 x 512x512 W^T bf16

    prep_k<<<2305, 256, 0, stream>>>(Wq, Wk, Wv, Wpos, Wo, pos_e, xlens,
                                     wt, pe, out + (size_t)8192 * 512);
    ln_k<<<2048, 256, 0, stream>>>(x, gam, bet, xn);
    // fused QKV: M=8192, N=3*512
    gemm_k<<<dim3(64, 12), 256, 0, stream>>>(xn, wt, wt + 262144, wt + 2 * 262144,
                                             bq, bk, bv, 0, qb, kb, vb, nullptr);
    // P: M=2047(padded 2048), N=512
    gemm_k<<<dim3(16, 4), 256, 0, stream>>>(pe, wt + 3 * 262144, nullptr, nullptr,
                                            nullptr, nullptr, nullptr, 1,
                                            pb, nullptr, nullptr, nullptr);
    attn_k<<<dim3(16, 64), 256, 0, stream>>>(qb, kb, vb, pb, pbu, pbv, xlens, xn);
    // out = AO @ WoT + bo (fp32)
    gemm_k<<<dim3(64, 4), 256, 0, stream>>>(xn, wt + 4 * 262144, nullptr, nullptr,
                                            bo, nullptr, nullptr, 2,
                                            nullptr, nullptr, nullptr, out);
}

// Round 2
// 145.285 us; speedup vs baseline: 1.5966x; 1.5966x over previous
//
#include <hip/hip_runtime.h>
#include <stdint.h>

// ConformerSelfAttention (B=8,T=1024,D=512,H=8,DK=64) for gfx950. Round 2.
// prep(W^T->bf16, pos_emb->bf16, xlens tail) -> LN -> fused QKV+P GEMM
// (global_load_lds, V stored transposed) -> flash rel-pos attn (swizzled LDS,
// 80-col bd band, circular P) -> out GEMM -> d_out fp32.

typedef __attribute__((ext_vector_type(8))) short s8v;
typedef __attribute__((ext_vector_type(4))) short s4v;
typedef __attribute__((ext_vector_type(4))) float f4v;
typedef unsigned short u16;

#define MFMA(a, b, c) __builtin_amdgcn_mfma_f32_16x16x32_bf16((a), (b), (c), 0, 0, 0)

__device__ __forceinline__ float bf2f(u16 u) {
    union { unsigned i; float f; } w; w.i = ((unsigned)u) << 16; return w.f;
}
__device__ __forceinline__ u16 f2bf(float f) {   // RTNE (outputs)
    union { float f; unsigned i; } w; w.f = f;
    return (u16)((w.i + 0x7FFFu + ((w.i >> 16) & 1u)) >> 16);
}
__device__ __forceinline__ u16 f2bt(float f) {   // trunc (intermediates; huge tolerance)
    union { float f; unsigned i; } w; w.f = f;
    return (u16)(w.i >> 16);
}
__device__ __forceinline__ void gld16(const void* g, void* l) {
    __builtin_amdgcn_global_load_lds(
        (const __attribute__((address_space(1))) unsigned int*)g,
        (__attribute__((address_space(3))) unsigned int*)l, 16, 0, 0);
}

// ---------------- prep: W^T->bf16 (5 mats), pos_emb->bf16, xlens tail ----------------
__global__ __launch_bounds__(256) void prep_k(
    const float* __restrict__ Wq, const float* __restrict__ Wk, const float* __restrict__ Wv,
    const float* __restrict__ Wpos, const float* __restrict__ Wo,
    const float* __restrict__ pos_emb, const int* __restrict__ xlens,
    u16* __restrict__ wt, u16* __restrict__ pe, float* __restrict__ tail)
{
    int bid = blockIdx.x, tid = threadIdx.x;
    if (bid < 1280) {
        __shared__ float lt[32][33];
        int mat = bid >> 8, tile = bid & 255;
        int kt = (tile >> 4) << 5, nt = (tile & 15) << 5;
        const float* W = mat == 0 ? Wq : mat == 1 ? Wk : mat == 2 ? Wv : mat == 3 ? Wpos : Wo;
        int ty = tid >> 3, tx = tid & 7;
        float4 vv = *(const float4*)&W[(kt + ty) * 512 + nt + tx * 4];
        lt[ty][tx * 4 + 0] = vv.x; lt[ty][tx * 4 + 1] = vv.y;
        lt[ty][tx * 4 + 2] = vv.z; lt[ty][tx * 4 + 3] = vv.w;
        __syncthreads();
        int nl = tid >> 3, k4 = (tid & 7) * 4;
        union { s4v v; u16 u[4]; } ob;
        #pragma unroll
        for (int e = 0; e < 4; ++e) ob.u[e] = f2bf(lt[k4 + e][nl]);
        *(s4v*)&wt[mat * 262144 + (nt + nl) * 512 + kt + k4] = ob.v;
    } else if (bid < 2304) {
        int i = (bid - 1280) * 1024 + tid * 4;
        union { s4v v; u16 u[4]; } ob;
        if (i < 2047 * 512) {
            float4 vv = *(const float4*)&pos_emb[i];
            ob.u[0] = f2bf(vv.x); ob.u[1] = f2bf(vv.y);
            ob.u[2] = f2bf(vv.z); ob.u[3] = f2bf(vv.w);
        } else {
            ob.u[0] = ob.u[1] = ob.u[2] = ob.u[3] = 0;
        }
        *(s4v*)&pe[i] = ob.v;
    } else {
        if (tid < 8) tail[tid] = (float)xlens[tid];
    }
}

// ---------------- LayerNorm: one wave per token, bf16 out ----------------
__global__ __launch_bounds__(256) void ln_k(
    const float* __restrict__ x, const float* __restrict__ gamma,
    const float* __restrict__ beta, u16* __restrict__ xn)
{
    int tok = blockIdx.x * 4 + (threadIdx.x >> 6);
    int l = threadIdx.x & 63;
    const float* xr = x + (size_t)tok * 512 + l * 8;
    float v[8];
    {
        float4 a = *(const float4*)xr; float4 b = *(const float4*)(xr + 4);
        v[0] = a.x; v[1] = a.y; v[2] = a.z; v[3] = a.w;
        v[4] = b.x; v[5] = b.y; v[6] = b.z; v[7] = b.w;
    }
    float s = 0.f, q = 0.f;
    #pragma unroll
    for (int e = 0; e < 8; ++e) { s += v[e]; q += v[e] * v[e]; }
    #pragma unroll
    for (int off = 1; off < 64; off <<= 1) { s += __shfl_xor(s, off); q += __shfl_xor(q, off); }
    float mean = s * (1.f / 512.f);
    float var = q * (1.f / 512.f) - mean * mean;
    float inv = rsqrtf(var + 1e-5f);
    union { s8v v; u16 u[8]; } ob;
    #pragma unroll
    for (int e = 0; e < 8; ++e)
        ob.u[e] = f2bf((v[e] - mean) * inv * gamma[l * 8 + e] + beta[l * 8 + e]);
    *(s8v*)&xn[(size_t)tok * 512 + l * 8] = ob.v;
}

// ---------------- GEMM (m97 structure): 128x128 tile, BK=32, global_load_lds ----------
// mode 0 grid(64,13): y<12 fused QKV (+bias, per-head layout; V transposed);
//                     y==12: P = pe @ WposT -> pb (H,2047,DK)
// mode 2 grid(64,4): out = AO @ WoT + bo (fp32)
__global__ __launch_bounds__(256) void gemm_k(
    const u16* __restrict__ A, const u16* __restrict__ Ap, const u16* __restrict__ wt,
    const float* __restrict__ bq, const float* __restrict__ bk, const float* __restrict__ bv,
    int mode, u16* __restrict__ qo, u16* __restrict__ ko, u16* __restrict__ vtg,
    u16* __restrict__ pb, float* __restrict__ of)
{
    __shared__ u16 Al[128 * 32];
    __shared__ u16 Bl[128 * 32];
    int tid = threadIdx.x, l = tid & 63, wid = tid >> 6;
    int wr = wid >> 1, wc = wid & 1, r = l & 15, g = l >> 4;
    int m0, nb, mat;
    const u16 *Ag, *Wg;
    if (mode == 0) {
        if (blockIdx.y < 12) {
            m0 = blockIdx.x << 7; int n0 = blockIdx.y << 7;
            mat = n0 >> 9; nb = n0 & 511; Ag = A; Wg = wt + mat * 262144;
        } else {
            mat = 3; m0 = (blockIdx.x & 15) << 7; nb = (blockIdx.x >> 4) << 7;
            Ag = Ap; Wg = wt + 3 * 262144;
        }
    } else {
        mat = 4; m0 = blockIdx.x << 7; nb = blockIdx.y << 7; Ag = A; Wg = wt + 4 * 262144;
    }

    int rw4 = l >> 2;                 // row within 16-row stage group (64B rows)
    int cs = (l & 3) << 3;            // source col elems (linear; matches m97)
    int offA = g << 3;                // frag read col elems

    f4v zero = {0.f, 0.f, 0.f, 0.f};
    f4v acc[4][4];
    #pragma unroll
    for (int i = 0; i < 4; ++i)
        #pragma unroll
        for (int j = 0; j < 4; ++j) acc[i][j] = zero;

    for (int k0 = 0; k0 < 512; k0 += 32) {
        __syncthreads();
        #pragma unroll
        for (int it = 0; it < 2; ++it) {
            int rowb = wid * 32 + it * 16;
            gld16(&Ag[(size_t)(m0 + rowb + rw4) * 512 + k0 + cs], &Al[rowb * 32]);
            gld16(&Wg[(size_t)(nb + rowb + rw4) * 512 + k0 + cs], &Bl[rowb * 32]);
        }
        __syncthreads();
        s8v af[4], bfv[4];
        #pragma unroll
        for (int i = 0; i < 4; ++i) af[i] = *(const s8v*)&Al[(wr * 64 + i * 16 + r) * 32 + offA];
        #pragma unroll
        for (int j = 0; j < 4; ++j) bfv[j] = *(const s8v*)&Bl[(wc * 64 + j * 16 + r) * 32 + offA];
        #pragma unroll
        for (int i = 0; i < 4; ++i)
            #pragma unroll
            for (int j = 0; j < 4; ++j) acc[i][j] = MFMA(af[i], bfv[j], acc[i][j]);
    }

    #pragma unroll
    for (int i = 0; i < 4; ++i)
        #pragma unroll
        for (int j = 0; j < 4; ++j) {
            int ncol = nb + wc * 64 + j * 16 + r;
            int mbase = m0 + wr * 64 + i * 16 + g * 4;
            if (mode == 2) {
                float bb = bq[ncol];
                #pragma unroll
                for (int jj = 0; jj < 4; ++jj)
                    of[(size_t)(mbase + jj) * 512 + ncol] = acc[i][j][jj] + bb;
            } else if (mat == 3) {
                int hh = ncol >> 6, dk = ncol & 63;
                #pragma unroll
                for (int jj = 0; jj < 4; ++jj) {
                    int m = mbase + jj;
                    if (m < 2047) pb[(hh * 2047 + m) * 64 + dk] = f2bf(acc[i][j][jj]);
                }
            } else if (mat == 2) {
                float bb = bv[ncol];
                int hh = ncol >> 6, dk = ncol & 63;
                int bbx = mbase >> 10, t = mbase & 1023;
                union { s4v v; u16 u[4]; } pk;
                #pragma unroll
                for (int jj = 0; jj < 4; ++jj) pk.u[jj] = f2bf(acc[i][j][jj] + bb);
                *(s4v*)&vtg[((size_t)(bbx * 8 + hh) * 64 + dk) * 1024 + t] = pk.v;
            } else {
                float bb = (mat == 0 ? bq : bk)[ncol];
                u16* dst = (mat == 0) ? qo : ko;
                int hh = ncol >> 6, dk = ncol & 63;
                #pragma unroll
                for (int jj = 0; jj < 4; ++jj) {
                    int m = mbase + jj;
                    int bbx = m >> 10, t = m & 1023;
                    dst[((size_t)(bbx * 8 + hh) * 1024 + t) * 64 + dk] = f2bf(acc[i][j][jj] + bb);
                }
            }
        }
}

// ---------------- flash rel-pos attention (v2) ----------------
// grid (16 t-tiles, 64 b*h); 4 waves x 16 t-rows. K/V^T/P staged via
// global_load_lds with XOR-swizzled source (blk' = blk ^ (row&7)); circular
// 128-row P window; per-wave 16x80 bd band spilled transposed (b64 packs).
__global__ __launch_bounds__(256, 3) void attn_k(
    const u16* __restrict__ q, const u16* __restrict__ k, const u16* __restrict__ vtg,
    const u16* __restrict__ p, const float* __restrict__ pbu, const float* __restrict__ pbv,
    const int* __restrict__ xlens, u16* __restrict__ ao)
{
    __shared__ u16 Ks[64 * 64];
    __shared__ u16 Vt[64 * 64];
    __shared__ u16 Ps[128 * 64];
    __shared__ u16 Tb[4][1600];   // per-wave: bd band [80 cols][20], then P [16][72]

    int tid = threadIdx.x, l = tid & 63, wid = tid >> 6;
    int r = l & 15, g = l >> 4, kq = g << 3;
    int t0 = blockIdx.x << 6;
    int bh = blockIdx.y, b = bh >> 3, h = bh & 7;
    int xlen = xlens[b];
    const u16* qh = q + (size_t)bh * 65536;
    const u16* kh = k + (size_t)bh * 65536;
    const u16* vh = vtg + (size_t)bh * 65536;
    const u16* ph = p + (size_t)h * 2047 * 64;

    int rw8 = l >> 3;
    int csw = ((l & 7) ^ rw8) << 3;            // pre-swizzled source col (elems)
    int off0 = ((g ^ (r & 7)) << 3);           // swizzled read col, ks=0 (blk g)
    int off1 = (((4 + g) ^ (r & 7)) << 3);     // ks=1 (blk 4+g)

    // Q frags + pos biases (once per block)
    s8v qu[2], qv2[2];
    #pragma unroll
    for (int ks = 0; ks < 2; ++ks) {
        union { s8v v; u16 u[8]; } src, du, dv;
        src.v = *(const s8v*)&qh[(t0 + wid * 16 + r) * 64 + ks * 32 + kq];
        float4 u0 = *(const float4*)&pbu[h * 64 + ks * 32 + kq];
        float4 u1 = *(const float4*)&pbu[h * 64 + ks * 32 + kq + 4];
        float4 v0 = *(const float4*)&pbv[h * 64 + ks * 32 + kq];
        float4 v1 = *(const float4*)&pbv[h * 64 + ks * 32 + kq + 4];
        float ub[8] = {u0.x, u0.y, u0.z, u0.w, u1.x, u1.y, u1.z, u1.w};
        float vb[8] = {v0.x, v0.y, v0.z, v0.w, v1.x, v1.y, v1.z, v1.w};
        #pragma unroll
        for (int e = 0; e < 8; ++e) {
            float qf = bf2f(src.u[e]);
            du.u[e] = f2bf(qf + ub[e]);
            dv.u[e] = f2bf(qf + vb[e]);
        }
        qu[ks] = du.v; qv2[ks] = dv.v;
    }

    float mst[4] = {-1e30f, -1e30f, -1e30f, -1e30f};
    float lst[4] = {0.f, 0.f, 0.f, 0.f};
    f4v zero = {0.f, 0.f, 0.f, 0.f};
    f4v o[4] = {zero, zero, zero, zero};
    u16* tb = &Tb[wid][0];
    int nst = (xlen + 63) >> 6;

    for (int s0i = 0; s0i < nst; ++s0i) {
        int s0 = s0i << 6;
        __syncthreads();
        // stage K and V^T (8 rows x 128B per instr, swizzled source)
        #pragma unroll
        for (int it = 0; it < 2; ++it) {
            int rowb = wid * 16 + it * 8;
            gld16(&kh[(s0 + rowb + rw8) * 64 + csw], &Ks[rowb * 64]);
            gld16(&vh[(rowb + rw8) * 1024 + s0 + csw], &Vt[rowb * 64]);
        }
        // stage P window (circular 128 rows; 64 new per tile)
        if (s0i == 0) {
            #pragma unroll
            for (int it = 0; it < 4; ++it) {
                int idx = wid * 32 + it * 8;
                int gg = idx + rw8 + 960 - t0;          // in [0, 1087]
                gld16(&ph[gg * 64 + csw], &Ps[idx * 64]);
            }
        } else {
            int mlo = s0 + 64;
            #pragma unroll
            for (int it = 0; it < 2; ++it) {
                int idx = wid * 16 + it * 8;
                int gg = mlo + idx + rw8 + 960 - t0;
                gg = gg > 2046 ? 2046 : gg;             // pad rows never gathered
                gld16(&ph[gg * 64 + csw], &Ps[((mlo & 127) + idx) * 64]);
            }
        }
        __syncthreads();

        // content scores (q+u)@K^T : 16x64 per wave
        f4v st4[4];
        #pragma unroll
        for (int nf = 0; nf < 4; ++nf) {
            int row = (nf * 16 + r) * 64;
            f4v a = MFMA(qu[0], *(const s8v*)&Ks[row + off0], zero);
            st4[nf] = MFMA(qu[1], *(const s8v*)&Ks[row + off1], a);
        }
        // positional band (q+v)@P^T : 16x80 per wave, spilled transposed (b64)
        int pw = (s0 + 48 - wid * 16) & 127;
        #pragma unroll
        for (int pf = 0; pf < 5; ++pf) {
            int prow = ((pw + pf * 16 + r) & 127) * 64;
            f4v a = MFMA(qv2[0], *(const s8v*)&Ps[prow + off0], zero);
            a = MFMA(qv2[1], *(const s8v*)&Ps[prow + off1], a);
            union { s4v v; u16 u[4]; } pk;
            #pragma unroll
            for (int jj = 0; jj < 4; ++jj) pk.u[jj] = f2bt(a[jj]);
            *(s4v*)&tb[(pf * 16 + r) * 20 + g * 4] = pk.v;
        }
        asm volatile("s_waitcnt lgkmcnt(0)" ::: "memory");
        __builtin_amdgcn_sched_barrier(0);
        // rel-shift gather + mask + scale
        float sv_[4][4];
        #pragma unroll
        for (int j = 0; j < 4; ++j) {
            int tl = g * 4 + j;
            #pragma unroll
            for (int nf = 0; nf < 4; ++nf) {
                int si = nf * 16 + r;
                float bd = bf2f(tb[(si + 15 - tl) * 20 + tl]);
                float val = (st4[nf][j] + bd) * 0.125f;
                sv_[nf][j] = (s0 + si >= xlen) ? -1e9f : val;
            }
        }
        // online softmax (reduce over 16 r-lanes)
        float pr[4][4];
        #pragma unroll
        for (int j = 0; j < 4; ++j) {
            float mx = fmaxf(fmaxf(sv_[0][j], sv_[1][j]), fmaxf(sv_[2][j], sv_[3][j]));
            mx = fmaxf(mx, __shfl_xor(mx, 1));
            mx = fmaxf(mx, __shfl_xor(mx, 2));
            mx = fmaxf(mx, __shfl_xor(mx, 4));
            mx = fmaxf(mx, __shfl_xor(mx, 8));
            float mnew = fmaxf(mst[j], mx);
            float alpha = __expf(mst[j] - mnew);
            float rs = 0.f;
            #pragma unroll
            for (int nf = 0; nf < 4; ++nf) {
                float e_ = __expf(sv_[nf][j] - mnew); pr[nf][j] = e_; rs += e_;
            }
            rs += __shfl_xor(rs, 1); rs += __shfl_xor(rs, 2);
            rs += __shfl_xor(rs, 4); rs += __shfl_xor(rs, 8);
            lst[j] = lst[j] * alpha + rs; mst[j] = mnew;
            #pragma unroll
            for (int i = 0; i < 4; ++i) o[i][j] *= alpha;
        }
        asm volatile("" ::: "memory");
        // P -> per-wave LDS [16][72] (reuses tb), read back as A-frags
        #pragma unroll
        for (int nf = 0; nf < 4; ++nf)
            #pragma unroll
            for (int j = 0; j < 4; ++j)
                tb[(g * 4 + j) * 72 + nf * 16 + r] = f2bt(pr[nf][j]);
        asm volatile("s_waitcnt lgkmcnt(0)" ::: "memory");
        __builtin_amdgcn_sched_barrier(0);
        s8v pa0 = *(const s8v*)&tb[r * 72 + kq];
        s8v pa1 = *(const s8v*)&tb[r * 72 + 32 + kq];
        // O += P @ V (B-frags from swizzled V^T)
        #pragma unroll
        for (int i = 0; i < 4; ++i) {
            int vrow = (i * 16 + r) * 64;
            o[i] = MFMA(pa0, *(const s8v*)&Vt[vrow + off0], o[i]);
            o[i] = MFMA(pa1, *(const s8v*)&Vt[vrow + off1], o[i]);
        }
    }
    // normalize + write (B,T,D) bf16
    #pragma unroll
    for (int j = 0; j < 4; ++j) {
        float inv = 1.f / lst[j];
        int t = t0 + wid * 16 + g * 4 + j;
        #pragma unroll
        for (int i = 0; i < 4; ++i)
            ao[((size_t)(b * 1024 + t)) * 512 + h * 64 + i * 16 + r] = f2bf(o[i][j] * inv);
    }
}

// ---------------- launch ----------------
extern "C" void kernel_launch(void* const* d_in, const int* in_sizes, int n_in,
                              void* d_out, int out_size, void* d_ws, size_t ws_size,
                              hipStream_t stream)
{
    (void)in_sizes; (void)n_in; (void)out_size; (void)ws_size;
    const float* x     = (const float*)d_in[0];
    const int*   xlens = (const int*)d_in[1];
    const float* pos_e = (const float*)d_in[2];
    const float* gam   = (const float*)d_in[3];
    const float* bet   = (const float*)d_in[4];
    const float* Wq    = (const float*)d_in[5];
    const float* bq    = (const float*)d_in[6];
    const float* Wk    = (const float*)d_in[7];
    const float* bk    = (const float*)d_in[8];
    const float* Wv    = (const float*)d_in[9];
    const float* bv    = (const float*)d_in[10];
    const float* Wpos  = (const float*)d_in[11];
    const float* pbu   = (const float*)d_in[12];
    const float* pbv   = (const float*)d_in[13];
    const float* Wo    = (const float*)d_in[14];
    const float* bo    = (const float*)d_in[15];
    float* out = (float*)d_out;

    char* ws = (char*)d_ws;
    u16* xn  = (u16*)(ws);                    // 8 MiB; LN out, later attn out
    u16* qb  = (u16*)(ws + 8388608);          // (B,H,T,DK)
    u16* kb  = (u16*)(ws + 16777216);         // (B,H,T,DK)
    u16* vtg = (u16*)(ws + 25165824);         // (B,H,DK,T) transposed
    u16* pbf = (u16*)(ws + 33554432);         // (H,2047,DK)
    u16* pe  = (u16*)(ws + 35651584);         // pos_emb bf16, 2048 rows
    u16* wt  = (u16*)(ws + 37748736);         // 5 x 512x512 W^T bf16

    prep_k<<<2305, 256, 0, stream>>>(Wq, Wk, Wv, Wpos, Wo, pos_e, xlens,
                                     wt, pe, out + (size_t)8192 * 512);
    ln_k<<<2048, 256, 0, stream>>>(x, gam, bet, xn);
    // fused QKV (y<12) + P (y==12)
    gemm_k<<<dim3(64, 13), 256, 0, stream>>>(xn, pe, wt, bq, bk, bv, 0,
                                             qb, kb, vtg, pbf, nullptr);
    attn_k<<<dim3(16, 64), 256, 0, stream>>>(qb, kb, vtg, pbf, pbu, pbv, xlens, xn);
    // out = AO @ WoT + bo (fp32)
    gemm_k<<<dim3(64, 4), 256, 0, stream>>>(xn, nullptr, wt, bo, nullptr, nullptr, 2,
                                            nullptr, nullptr, nullptr, nullptr, out);
}